// Round 1
// baseline (152.744 us; speedup 1.0000x reference)
//
#include <hip/hip_runtime.h>

#define NBATCH 8192
#define NELEC  16
#define NMO    32
#define NCONF  64
#define NS     8   // NUP == NDOWN == 8

// Solve one spin channel: gather A,D (8x8) from MO/d2MO rows [rowoff..rowoff+7]
// at columns cols[0..7]; return det(A) and tr(A^{-1} D).
__device__ __forceinline__ void solve8(const float* __restrict__ MOb,
                                       const float* __restrict__ d2b,
                                       int rowoff, const int (&cols)[NS],
                                       float& det_out, float& tr_out)
{
    float A[NS][NS], D[NS][NS];
    #pragma unroll
    for (int i = 0; i < NS; ++i) {
        const float* mrow = MOb + (rowoff + i) * NMO;
        const float* drow = d2b + (rowoff + i) * NMO;
        #pragma unroll
        for (int j = 0; j < NS; ++j) {
            A[i][j] = mrow[cols[j]];
            D[i][j] = drow[cols[j]];
        }
    }

    float sign = 1.0f;
    float diaginv[NS];

    #pragma unroll
    for (int k = 0; k < NS; ++k) {
        // partial pivoting via pairwise conditional swaps (keeps static indexing)
        #pragma unroll
        for (int r = k + 1; r < NS; ++r) {
            bool sw = fabsf(A[r][k]) > fabsf(A[k][k]);
            #pragma unroll
            for (int c2 = k; c2 < NS; ++c2) {
                float t = A[k][c2];
                A[k][c2] = sw ? A[r][c2] : A[k][c2];
                A[r][c2] = sw ? t        : A[r][c2];
            }
            #pragma unroll
            for (int c2 = 0; c2 < NS; ++c2) {
                float t = D[k][c2];
                D[k][c2] = sw ? D[r][c2] : D[k][c2];
                D[r][c2] = sw ? t        : D[r][c2];
            }
            sign = sw ? -sign : sign;
        }
        float pinv = __builtin_amdgcn_rcpf(A[k][k]);
        diaginv[k] = pinv;
        #pragma unroll
        for (int r = k + 1; r < NS; ++r) {
            float m = A[r][k] * pinv;
            #pragma unroll
            for (int c2 = k + 1; c2 < NS; ++c2)
                A[r][c2] = fmaf(-m, A[k][c2], A[r][c2]);
            #pragma unroll
            for (int c2 = 0; c2 < NS; ++c2)
                D[r][c2] = fmaf(-m, D[k][c2], D[r][c2]);
        }
    }

    float det = sign;
    #pragma unroll
    for (int k = 0; k < NS; ++k) det *= A[k][k];

    // back substitution: for RHS column j we only need x[j]
    float tr = 0.0f;
    #pragma unroll
    for (int j = 0; j < NS; ++j) {
        float x[NS];
        #pragma unroll
        for (int i = NS - 1; i >= 0; --i) {
            if (i < j) continue;   // unrolled: dead iterations dropped
            float acc = D[i][j];
            #pragma unroll
            for (int c2 = i + 1; c2 < NS; ++c2)
                acc = fmaf(-A[i][c2], x[c2], acc);
            x[i] = acc * diaginv[i];
        }
        tr += x[j];
    }

    det_out = det;
    tr_out  = tr;
}

__global__ __launch_bounds__(256)
void KineticPooling_kernel(const float* __restrict__ MO,
                           const float* __restrict__ d2MO,
                           const int*   __restrict__ cfg_up,
                           const int*   __restrict__ cfg_dn,
                           float*       __restrict__ out)
{
    const int tid = threadIdx.x;
    const int c   = tid & 63;                 // config index (lane)
    const int wb  = tid >> 6;                 // wave (batch) within block
    const int b   = blockIdx.x * 4 + wb;      // batch index

    // configs: row c is 8 ints = 32 B, aligned -> two int4 loads each
    int4 cu0 = ((const int4*)cfg_up)[c * 2 + 0];
    int4 cu1 = ((const int4*)cfg_up)[c * 2 + 1];
    int4 cd0 = ((const int4*)cfg_dn)[c * 2 + 0];
    int4 cd1 = ((const int4*)cfg_dn)[c * 2 + 1];
    const int cu[NS] = {cu0.x, cu0.y, cu0.z, cu0.w, cu1.x, cu1.y, cu1.z, cu1.w};
    const int cd[NS] = {cd0.x, cd0.y, cd0.z, cd0.w, cd1.x, cd1.y, cd1.z, cd1.w};

    const float* MOb = MO   + (size_t)b * NELEC * NMO;
    const float* d2b = d2MO + (size_t)b * NELEC * NMO;

    float detU, trU, detD, trD;
    solve8(MOb, d2b, 0,  cu, detU, trU);
    solve8(MOb, d2b, NS, cd, detD, trD);

    out[(size_t)b * NCONF + c] = -0.5f * (trU + trD) * detU * detD;
}

extern "C" void kernel_launch(void* const* d_in, const int* in_sizes, int n_in,
                              void* d_out, int out_size, void* d_ws, size_t ws_size,
                              hipStream_t stream)
{
    const float* MO     = (const float*)d_in[0];
    const float* d2MO   = (const float*)d_in[1];
    const int*   cfg_up = (const int*)d_in[2];
    const int*   cfg_dn = (const int*)d_in[3];
    float* out = (float*)d_out;

    dim3 grid(NBATCH / 4);   // 2048 blocks, 4 batches (waves) per block
    dim3 block(256);
    KineticPooling_kernel<<<grid, block, 0, stream>>>(MO, d2MO, cfg_up, cfg_dn, out);
}

// Round 2
// 97.678 us; speedup vs baseline: 1.5638x; 1.5638x over previous
//
#include <hip/hip_runtime.h>

#define NBATCH 8192
#define NELEC  16
#define NMO    32
#define NCONF  64
#define NS     8          // NUP == NDOWN == 8
#define TSTR   20         // transposed row stride in floats (80 B: 16B-aligned, bank-spreading pad)
#define TSZ    (NMO * TSTR)

// Solve one spin channel on TRANSPOSED fragments:
//   A'[j][i] = MO[b, eoff+i, cols[j]]  (= A^T), same for D'.
//   tr(A^-1 D) = tr(A'^-1 D'),  det(A) = det(A').
// LU without pivoting (random Gaussian 8x8; error budget is ~2% of global absmax).
__device__ __forceinline__ void solve8T(const float* __restrict__ MOT,
                                        const float* __restrict__ D2T,
                                        const int (&cols)[NS], int eoff,
                                        float& det_out, float& tr_out)
{
    float A[NS][NS], D[NS][NS];
    #pragma unroll
    for (int j = 0; j < NS; ++j) {
        const float4* pa = (const float4*)(MOT + cols[j] * TSTR + eoff);
        const float4* pd = (const float4*)(D2T + cols[j] * TSTR + eoff);
        float4 a0 = pa[0], a1 = pa[1];
        float4 d0 = pd[0], d1 = pd[1];
        A[j][0] = a0.x; A[j][1] = a0.y; A[j][2] = a0.z; A[j][3] = a0.w;
        A[j][4] = a1.x; A[j][5] = a1.y; A[j][6] = a1.z; A[j][7] = a1.w;
        D[j][0] = d0.x; D[j][1] = d0.y; D[j][2] = d0.z; D[j][3] = d0.w;
        D[j][4] = d1.x; D[j][5] = d1.y; D[j][6] = d1.z; D[j][7] = d1.w;
    }

    float det = 1.0f;
    #pragma unroll
    for (int k = 0; k < NS; ++k) {
        det *= A[k][k];
        float pinv = __builtin_amdgcn_rcpf(A[k][k]);
        A[k][k] = pinv;                      // reuse slot: back-sub needs 1/diag
        #pragma unroll
        for (int r = k + 1; r < NS; ++r) {
            float m = A[r][k] * pinv;
            #pragma unroll
            for (int c2 = k + 1; c2 < NS; ++c2)
                A[r][c2] = fmaf(-m, A[k][c2], A[r][c2]);
            #pragma unroll
            for (int c2 = 0; c2 < NS; ++c2)
                D[r][c2] = fmaf(-m, D[k][c2], D[r][c2]);
        }
    }

    // back substitution: for RHS column j of D', only x[j] contributes to trace
    float tr = 0.0f;
    #pragma unroll
    for (int j = 0; j < NS; ++j) {
        float x[NS];
        #pragma unroll
        for (int i = NS - 1; i >= 0; --i) {
            if (i < j) continue;             // statically dropped
            float acc = D[i][j];
            #pragma unroll
            for (int c2 = i + 1; c2 < NS; ++c2)
                acc = fmaf(-A[i][c2], x[c2], acc);
            x[i] = acc * A[i][i];            // A[i][i] holds pinv_i
        }
        tr += x[j];
    }

    det_out = det;
    tr_out  = tr;
}

__global__ __launch_bounds__(256)
void KineticPooling_kernel(const float* __restrict__ MO,
                           const float* __restrict__ d2MO,
                           const int*   __restrict__ cfg_up,
                           const int*   __restrict__ cfg_dn,
                           float*       __restrict__ out)
{
    __shared__ float smem[4][2][TSZ];        // [wave][MO^T / d2MO^T][32 x 20]

    const int tid  = threadIdx.x;
    const int lane = tid & 63;               // config index
    const int wb   = tid >> 6;               // wave within block
    const int b    = blockIdx.x * 4 + wb;    // batch

    float* MOT = smem[wb][0];
    float* D2T = smem[wb][1];

    const float* MOb = MO   + (size_t)b * NELEC * NMO;
    const float* d2b = d2MO + (size_t)b * NELEC * NMO;

    // Stage MO^T and d2MO^T for this batch: 512 floats each.
    // Chunk q: lane covers row r = q*8 + lane/8, cols c..c+3 = (lane%8)*4.
    #pragma unroll
    for (int q = 0; q < 2; ++q) {
        int r = q * 8 + (lane >> 3);
        int c = (lane & 7) * 4;
        float4 v = *(const float4*)(MOb + r * NMO + c);
        float4 w = *(const float4*)(d2b + r * NMO + c);
        MOT[(c + 0) * TSTR + r] = v.x;
        MOT[(c + 1) * TSTR + r] = v.y;
        MOT[(c + 2) * TSTR + r] = v.z;
        MOT[(c + 3) * TSTR + r] = v.w;
        D2T[(c + 0) * TSTR + r] = w.x;
        D2T[(c + 1) * TSTR + r] = w.y;
        D2T[(c + 2) * TSTR + r] = w.z;
        D2T[(c + 3) * TSTR + r] = w.w;
    }
    __syncthreads();

    // configs: row `lane` is 8 ints = 32 B -> two int4 loads each
    int4 cu0 = ((const int4*)cfg_up)[lane * 2 + 0];
    int4 cu1 = ((const int4*)cfg_up)[lane * 2 + 1];
    int4 cd0 = ((const int4*)cfg_dn)[lane * 2 + 0];
    int4 cd1 = ((const int4*)cfg_dn)[lane * 2 + 1];
    const int cu[NS] = {cu0.x, cu0.y, cu0.z, cu0.w, cu1.x, cu1.y, cu1.z, cu1.w};
    const int cd[NS] = {cd0.x, cd0.y, cd0.z, cd0.w, cd1.x, cd1.y, cd1.z, cd1.w};

    float detU, trU, detD, trD;
    solve8T(MOT, D2T, cu, 0,  detU, trU);
    solve8T(MOT, D2T, cd, NS, detD, trD);

    out[(size_t)b * NCONF + lane] = -0.5f * (trU + trD) * detU * detD;
}

extern "C" void kernel_launch(void* const* d_in, const int* in_sizes, int n_in,
                              void* d_out, int out_size, void* d_ws, size_t ws_size,
                              hipStream_t stream)
{
    const float* MO     = (const float*)d_in[0];
    const float* d2MO   = (const float*)d_in[1];
    const int*   cfg_up = (const int*)d_in[2];
    const int*   cfg_dn = (const int*)d_in[3];
    float* out = (float*)d_out;

    dim3 grid(NBATCH / 4);   // 2048 blocks, 4 batches (waves) per block
    dim3 block(256);
    KineticPooling_kernel<<<grid, block, 0, stream>>>(MO, d2MO, cfg_up, cfg_dn, out);
}

// Round 5
// 91.552 us; speedup vs baseline: 1.6684x; 1.0669x over previous
//
#include <hip/hip_runtime.h>

#define NBATCH 8192
#define NELEC  16
#define NMO    32
#define NCONF  64
#define NS     8          // NUP == NDOWN == 8
#define TSTR   20         // transposed row stride in floats (80 B: 16B-aligned)
#define TSZ    (NMO * TSTR)

// EXACT round-2 proven solve: gather A',D' (transposed 8x8 fragments) from LDS,
// LU of A' without pivoting (eliminating D' alongside), det + tr(A^-1 D) via
// partial back-substitution. DO NOT restructure this routine: the streamed-D
// variant (R3/R4) produced deterministic garbage (absmax 1.01e7) despite
// operation-level equivalence on paper — suspected unroll/codegen issue.
__device__ __forceinline__ void solve8T(const float* __restrict__ MOT,
                                        const float* __restrict__ D2T,
                                        const int (&cols)[NS], int eoff,
                                        float& det_out, float& tr_out)
{
    float A[NS][NS], D[NS][NS];
    #pragma unroll
    for (int j = 0; j < NS; ++j) {
        const float4* pa = (const float4*)(MOT + cols[j] * TSTR + eoff);
        const float4* pd = (const float4*)(D2T + cols[j] * TSTR + eoff);
        float4 a0 = pa[0], a1 = pa[1];
        float4 d0 = pd[0], d1 = pd[1];
        A[j][0] = a0.x; A[j][1] = a0.y; A[j][2] = a0.z; A[j][3] = a0.w;
        A[j][4] = a1.x; A[j][5] = a1.y; A[j][6] = a1.z; A[j][7] = a1.w;
        D[j][0] = d0.x; D[j][1] = d0.y; D[j][2] = d0.z; D[j][3] = d0.w;
        D[j][4] = d1.x; D[j][5] = d1.y; D[j][6] = d1.z; D[j][7] = d1.w;
    }

    float det = 1.0f;
    #pragma unroll
    for (int k = 0; k < NS; ++k) {
        det *= A[k][k];
        float pinv = __builtin_amdgcn_rcpf(A[k][k]);
        A[k][k] = pinv;                      // reuse slot: back-sub needs 1/diag
        #pragma unroll
        for (int r = k + 1; r < NS; ++r) {
            float m = A[r][k] * pinv;
            #pragma unroll
            for (int c2 = k + 1; c2 < NS; ++c2)
                A[r][c2] = fmaf(-m, A[k][c2], A[r][c2]);
            #pragma unroll
            for (int c2 = 0; c2 < NS; ++c2)
                D[r][c2] = fmaf(-m, D[k][c2], D[r][c2]);
        }
    }

    // back substitution: for RHS column j of D', only x[j] contributes to trace
    float tr = 0.0f;
    #pragma unroll
    for (int j = 0; j < NS; ++j) {
        float x[NS];
        #pragma unroll
        for (int i = NS - 1; i >= 0; --i) {
            if (i < j) continue;             // statically dropped
            float acc = D[i][j];
            #pragma unroll
            for (int c2 = i + 1; c2 < NS; ++c2)
                acc = fmaf(-A[i][c2], x[c2], acc);
            x[i] = acc * A[i][i];            // A[i][i] holds pinv_i
        }
        tr += x[j];
    }

    det_out = det;
    tr_out  = tr;
}

// 2 threads per (batch, config) pair: lane parity selects the spin channel.
// Halves each thread's serial LU chain vs R2; combine via __shfl_xor(…,1).
__global__ __launch_bounds__(256)
void kp_split_kernel(const float* __restrict__ MO,
                     const float* __restrict__ d2MO,
                     const int*   __restrict__ cfg_up,
                     const int*   __restrict__ cfg_dn,
                     float*       __restrict__ out)
{
    __shared__ float smem[2][2][TSZ];        // [batch-half][MO^T / d2MO^T][32 x 20]

    const int tid  = threadIdx.x;
    const int half = tid >> 7;               // batch within block (0/1)
    const int u    = tid & 127;              // id within the batch's 128 threads
    const int b    = blockIdx.x * 2 + half;  // batch index

    float* MOT = smem[half][0];
    float* D2T = smem[half][1];

    const float* MOb = MO   + (size_t)b * NELEC * NMO;
    const float* d2b = d2MO + (size_t)b * NELEC * NMO;

    // Stage MO^T and d2MO^T (512 floats each) with 128 threads: one float4 per
    // array per thread, fully coalesced. r = u/8 in 0..15, c = (u%8)*4.
    {
        int r = u >> 3;
        int c = (u & 7) * 4;
        float4 v = *(const float4*)(MOb + r * NMO + c);
        float4 w = *(const float4*)(d2b + r * NMO + c);
        MOT[(c + 0) * TSTR + r] = v.x;
        MOT[(c + 1) * TSTR + r] = v.y;
        MOT[(c + 2) * TSTR + r] = v.z;
        MOT[(c + 3) * TSTR + r] = v.w;
        D2T[(c + 0) * TSTR + r] = w.x;
        D2T[(c + 1) * TSTR + r] = w.y;
        D2T[(c + 2) * TSTR + r] = w.z;
        D2T[(c + 3) * TSTR + r] = w.w;
    }
    __syncthreads();

    const int cidx = u >> 1;                 // config index 0..63
    const int s    = u & 1;                  // 0 = up, 1 = down
    const int* cfg = s ? cfg_dn : cfg_up;
    int4 c0 = ((const int4*)cfg)[cidx * 2 + 0];
    int4 c1 = ((const int4*)cfg)[cidx * 2 + 1];
    const int cols[NS] = {c0.x, c0.y, c0.z, c0.w, c1.x, c1.y, c1.z, c1.w};

    float det, tr;
    solve8T(MOT, D2T, cols, s * NS, det, tr);

    // partner lane (u^1, same wave) holds the other spin channel
    float det_o = __shfl_xor(det, 1);
    float tr_o  = __shfl_xor(tr, 1);
    if (s == 0)
        out[(size_t)b * NCONF + cidx] = -0.5f * (tr + tr_o) * det * det_o;
}

extern "C" void kernel_launch(void* const* d_in, const int* in_sizes, int n_in,
                              void* d_out, int out_size, void* d_ws, size_t ws_size,
                              hipStream_t stream)
{
    const float* MO     = (const float*)d_in[0];
    const float* d2MO   = (const float*)d_in[1];
    const int*   cfg_up = (const int*)d_in[2];
    const int*   cfg_dn = (const int*)d_in[3];
    float* out = (float*)d_out;

    dim3 grid(NBATCH / 2);   // 4096 blocks, 2 batches per block, 2 threads per pair
    dim3 block(256);
    kp_split_kernel<<<grid, block, 0, stream>>>(MO, d2MO, cfg_up, cfg_dn, out);
}

// Round 6
// 90.513 us; speedup vs baseline: 1.6875x; 1.0115x over previous
//
#include <hip/hip_runtime.h>

#define NBATCH 8192
#define NELEC  16
#define NMO    32
#define NCONF  64
#define NS     8          // NUP == NDOWN == 8
#define TSTR   20         // transposed row stride in floats (80 B: 16B-aligned)
#define TSZ    (NMO * TSTR)

// One spin channel on TRANSPOSED fragments: A'[j][i] = MO[b, eoff+i, cols[j]].
// det(A) = det(A');  tr(A^-1 d2A) = tr(A'^-1 D') = sum_k <col_k(A'^-1), row_k(D')>.
// Row k of D' (= d2MO[eoff+i][cols[k]], i contiguous) is a 2x-b128 LDS slice.
// Column k of A'^-1 comes from solving A' x = e_k against the in-register LU.
// D' is NEVER fully resident -> live set ~100 floats (vs 136 VGPR in R2/R5).
//
// R3/R4 POST-MORTEM (do not repeat): streaming "column j" via
// D2T + cols[j]*TSTR loads ROW j of D'. Rows of D' pair with COLUMNS of
// A'^-1 (this formulation); columns of D' pair with back-sub on D (R2's).
// Mixing the two produced deterministic garbage.
__device__ __forceinline__ void solve8T(const float* __restrict__ MOT,
                                        const float* __restrict__ D2T,
                                        const int (&cols)[NS], int eoff,
                                        float& det_out, float& tr_out)
{
    float A[NS][NS];
    #pragma unroll
    for (int j = 0; j < NS; ++j) {
        const float4* pa = (const float4*)(MOT + cols[j] * TSTR + eoff);
        float4 a0 = pa[0], a1 = pa[1];
        A[j][0] = a0.x; A[j][1] = a0.y; A[j][2] = a0.z; A[j][3] = a0.w;
        A[j][4] = a1.x; A[j][5] = a1.y; A[j][6] = a1.z; A[j][7] = a1.w;
    }

    // in-place LU (no pivot): A[k][k] = 1/u_kk, A[k][c>k] = u_kc, A[r][k<r] = l_rk
    float det = 1.0f;
    #pragma unroll
    for (int k = 0; k < NS; ++k) {
        det *= A[k][k];
        float pinv = __builtin_amdgcn_rcpf(A[k][k]);
        A[k][k] = pinv;
        #pragma unroll
        for (int r = k + 1; r < NS; ++r) {
            float m = A[r][k] * pinv;
            A[r][k] = m;
            #pragma unroll
            for (int c2 = k + 1; c2 < NS; ++c2)
                A[r][c2] = fmaf(-m, A[k][c2], A[r][c2]);
        }
    }

    // tr = sum_k  x(k) . row_k(D'),  where A' x(k) = e_k
    float tr = 0.0f;
    #pragma unroll
    for (int k = 0; k < NS; ++k) {
        // issue the D' row-k load early; compiler overlaps with the solve
        const float4* pd = (const float4*)(D2T + cols[k] * TSTR + eoff);
        float4 d0 = pd[0], d1 = pd[1];

        // forward: y = L^-1 e_k  (y_i = 0 for i<k, y_k = 1)
        float y[NS];
        y[k] = 1.0f;
        #pragma unroll
        for (int i = k + 1; i < NS; ++i) {
            float acc = A[i][k];                   // l_ik * y_k
            #pragma unroll
            for (int j2 = k + 1; j2 < i; ++j2)
                acc = fmaf(A[i][j2], y[j2], acc);
            y[i] = -acc;
        }

        // back: U x = y  (y_i = 0 for i<k handled statically)
        float x[NS];
        #pragma unroll
        for (int i = NS - 1; i >= 0; --i) {
            float acc = (i >= k) ? y[i] : 0.0f;    // k,i unroll-time constants
            #pragma unroll
            for (int c2 = i + 1; c2 < NS; ++c2)
                acc = fmaf(-A[i][c2], x[c2], acc);
            x[i] = acc * A[i][i];                  // A[i][i] = 1/u_ii
        }

        tr = fmaf(x[0], d0.x, tr);
        tr = fmaf(x[1], d0.y, tr);
        tr = fmaf(x[2], d0.z, tr);
        tr = fmaf(x[3], d0.w, tr);
        tr = fmaf(x[4], d1.x, tr);
        tr = fmaf(x[5], d1.y, tr);
        tr = fmaf(x[6], d1.z, tr);
        tr = fmaf(x[7], d1.w, tr);
    }

    det_out = det;
    tr_out  = tr;
}

// 2 threads per (batch, config) pair: lane parity selects the spin channel;
// combine via __shfl_xor(.,1). Halves each thread's serial LU chain.
__global__ __launch_bounds__(256)
void kp_split2_kernel(const float* __restrict__ MO,
                      const float* __restrict__ d2MO,
                      const int*   __restrict__ cfg_up,
                      const int*   __restrict__ cfg_dn,
                      float*       __restrict__ out)
{
    __shared__ float smem[2][2][TSZ];        // [batch-half][MO^T / d2MO^T][32 x 20]

    const int tid  = threadIdx.x;
    const int half = tid >> 7;               // batch within block (0/1)
    const int u    = tid & 127;              // id within the batch's 128 threads
    const int b    = blockIdx.x * 2 + half;  // batch index

    float* MOT = smem[half][0];
    float* D2T = smem[half][1];

    const float* MOb = MO   + (size_t)b * NELEC * NMO;
    const float* d2b = d2MO + (size_t)b * NELEC * NMO;

    // Stage MO^T and d2MO^T (512 floats each) with 128 threads: one float4 per
    // array per thread, fully coalesced. r = u/8 in 0..15, c = (u%8)*4.
    {
        int r = u >> 3;
        int c = (u & 7) * 4;
        float4 v = *(const float4*)(MOb + r * NMO + c);
        float4 w = *(const float4*)(d2b + r * NMO + c);
        MOT[(c + 0) * TSTR + r] = v.x;
        MOT[(c + 1) * TSTR + r] = v.y;
        MOT[(c + 2) * TSTR + r] = v.z;
        MOT[(c + 3) * TSTR + r] = v.w;
        D2T[(c + 0) * TSTR + r] = w.x;
        D2T[(c + 1) * TSTR + r] = w.y;
        D2T[(c + 2) * TSTR + r] = w.z;
        D2T[(c + 3) * TSTR + r] = w.w;
    }
    __syncthreads();

    const int cidx = u >> 1;                 // config index 0..63
    const int s    = u & 1;                  // 0 = up, 1 = down
    const int* cfg = s ? cfg_dn : cfg_up;
    int4 c0 = ((const int4*)cfg)[cidx * 2 + 0];
    int4 c1 = ((const int4*)cfg)[cidx * 2 + 1];
    const int cols[NS] = {c0.x, c0.y, c0.z, c0.w, c1.x, c1.y, c1.z, c1.w};

    float det, tr;
    solve8T(MOT, D2T, cols, s * NS, det, tr);

    // partner lane (u^1, same wave) holds the other spin channel
    float det_o = __shfl_xor(det, 1);
    float tr_o  = __shfl_xor(tr, 1);
    if (s == 0)
        out[(size_t)b * NCONF + cidx] = -0.5f * (tr + tr_o) * det * det_o;
}

extern "C" void kernel_launch(void* const* d_in, const int* in_sizes, int n_in,
                              void* d_out, int out_size, void* d_ws, size_t ws_size,
                              hipStream_t stream)
{
    const float* MO     = (const float*)d_in[0];
    const float* d2MO   = (const float*)d_in[1];
    const int*   cfg_up = (const int*)d_in[2];
    const int*   cfg_dn = (const int*)d_in[3];
    float* out = (float*)d_out;

    dim3 grid(NBATCH / 2);   // 4096 blocks, 2 batches per block, 2 threads per pair
    dim3 block(256);
    kp_split2_kernel<<<grid, block, 0, stream>>>(MO, d2MO, cfg_up, cfg_dn, out);
}

// Round 7
// 89.727 us; speedup vs baseline: 1.7023x; 1.0088x over previous
//
#include <hip/hip_runtime.h>

#define NBATCH 8192
#define NELEC  16
#define NMO    32
#define NCONF  64
#define NS     8          // NUP == NDOWN == 8
#define TSTR   20         // transposed row stride in floats (80 B: 16B-aligned)
#define TSZ    (NMO * TSTR)

typedef float v2f __attribute__((ext_vector_type(2)));

__device__ __forceinline__ v2f pkfma(v2f a, v2f b, v2f c) {
#if __has_builtin(__builtin_elementwise_fma)
    return __builtin_elementwise_fma(a, b, c);
#else
    return a * b + c;   // -ffp-contract=fast fuses; tolerance is generous anyway
#endif
}
__device__ __forceinline__ v2f bc2(float s) { return (v2f){s, s}; }
// element get/set on a v2f[4] row; index is unroll-time constant -> folds to subreg
__device__ __forceinline__ float getel2(const v2f (&R)[4], int j) {
    return (j & 1) ? R[j >> 1].y : R[j >> 1].x;
}
__device__ __forceinline__ void setel2(v2f (&R)[4], int j, float v) {
    if (j & 1) R[j >> 1].y = v; else R[j >> 1].x = v;
}

// One spin channel on TRANSPOSED fragments: A'[j][i] = MO[b, eoff+i, cols[j]].
// det(A)=det(A'); tr(A^-1 d2A) = sum_k <col_k(A'^-1), row_k(D')>, and row k of
// D' is a contiguous LDS slice. (R3/R4 lesson: rows of D' pair with columns of
// A'^-1 — do not mix with the back-sub-on-D formulation.)
// NEW (R7): packed-f32 (v_pk_fma_f32) throughout —
//   * LU row-updates packed over column pairs (rows contiguous in regs);
//   * the 8 unit-RHS solves packed over k pairs (k=2t,2t+1 in lo/hi halves).
// Same FLOPs/memory structure as R6, ~30% fewer issued VALU instructions.
__device__ __forceinline__ void solve8T(const float* __restrict__ MOT,
                                        const float* __restrict__ D2T,
                                        const int (&cols)[NS], int eoff,
                                        float& det_out, float& tr_out)
{
    v2f A2[NS][4];                    // row j, pair p = cols {2p, 2p+1}
    #pragma unroll
    for (int j = 0; j < NS; ++j) {
        const float4* pa = (const float4*)(MOT + cols[j] * TSTR + eoff);
        float4 a0 = pa[0], a1 = pa[1];
        A2[j][0] = (v2f){a0.x, a0.y};
        A2[j][1] = (v2f){a0.z, a0.w};
        A2[j][2] = (v2f){a1.x, a1.y};
        A2[j][3] = (v2f){a1.z, a1.w};
    }

    // In-place LU, no pivot. After step k: row k diag slot holds 1/u_kk,
    // cols >k of row k hold u_kc, col k of rows r>k holds l_rk.
    // Pair-updates may touch col k when k is even: it becomes a_rk - m*u_kk ~ 0
    // and is immediately overwritten with m (diag still holds u_kk at that
    // point; pinv is written only after the r-loop).
    float det = 1.0f;
    #pragma unroll
    for (int k = 0; k < NS; ++k) {
        float ukk = getel2(A2[k], k);
        det *= ukk;
        float pinv = __builtin_amdgcn_rcpf(ukk);
        #pragma unroll
        for (int r = k + 1; r < NS; ++r) {
            float m = getel2(A2[r], k) * pinv;
            v2f m2 = bc2(m);
            #pragma unroll
            for (int p = (k + 1) >> 1; p < 4; ++p)
                A2[r][p] = pkfma(-m2, A2[k][p], A2[r][p]);
            setel2(A2[r], k, m);
        }
        setel2(A2[k], k, pinv);
    }

    // tr = sum_k <x(k), row_k(D')> with A' x(k) = e_k; k's processed in pairs
    // (k0=2t lo half, k1=2t+1 hi half) — every solve op is one packed inst.
    float tr = 0.0f;
    #pragma unroll
    for (int t = 0; t < 4; ++t) {
        const int k0 = 2 * t, k1 = 2 * t + 1;

        const float4* pd0 = (const float4*)(D2T + cols[k0] * TSTR + eoff);
        const float4* pd1 = (const float4*)(D2T + cols[k1] * TSTR + eoff);
        float4 d00 = pd0[0], d01 = pd0[1];
        float4 d10 = pd1[0], d11 = pd1[1];
        const float dk0[NS] = {d00.x, d00.y, d00.z, d00.w, d01.x, d01.y, d01.z, d01.w};
        const float dk1[NS] = {d10.x, d10.y, d10.z, d10.w, d11.x, d11.y, d11.z, d11.w};

        // forward: y2[i] = { y_{k0}[i], y_{k1}[i] }, y = L^-1 e_k
        v2f y2[NS];
        y2[k0] = (v2f){1.0f, 0.0f};
        y2[k1] = (v2f){-getel2(A2[k1], k0), 1.0f};   // l_{k1,k0} below diag
        #pragma unroll
        for (int i = k1 + 1; i < NS; ++i) {
            v2f acc = (v2f){0.0f, 0.0f};
            #pragma unroll
            for (int j = k0; j < i; ++j)             // A-elem below diag = l_ij
                acc = pkfma(bc2(getel2(A2[i], j)), y2[j], acc);
            y2[i] = -acc;
        }

        // back: U x = y (dense over all rows; y2[i] = 0 for i < k0, and
        // y2[k0].y = 0 covers the k1 half's extra zero)
        v2f x2[NS];
        #pragma unroll
        for (int i = NS - 1; i >= 0; --i) {
            v2f acc = (i >= k0) ? y2[i] : (v2f){0.0f, 0.0f};
            #pragma unroll
            for (int c2 = i + 1; c2 < NS; ++c2)
                acc = pkfma(-bc2(getel2(A2[i], c2)), x2[c2], acc);
            x2[i] = acc * bc2(getel2(A2[i], i));     // diag slot = 1/u_ii
        }

        #pragma unroll
        for (int i = 0; i < NS; ++i) {
            tr = fmaf(x2[i].x, dk0[i], tr);
            tr = fmaf(x2[i].y, dk1[i], tr);
        }
    }

    det_out = det;
    tr_out  = tr;
}

// 2 threads per (batch, config) pair: lane parity = spin channel; combine via
// __shfl_xor(.,1). (R5: halves the serial LU chain vs one-thread-per-pair.)
__global__ __launch_bounds__(256)
void kp_pk_kernel(const float* __restrict__ MO,
                  const float* __restrict__ d2MO,
                  const int*   __restrict__ cfg_up,
                  const int*   __restrict__ cfg_dn,
                  float*       __restrict__ out)
{
    __shared__ float smem[2][2][TSZ];        // [batch-half][MO^T / d2MO^T][32 x 20]

    const int tid  = threadIdx.x;
    const int half = tid >> 7;               // batch within block (0/1)
    const int u    = tid & 127;              // id within the batch's 128 threads
    const int b    = blockIdx.x * 2 + half;  // batch index

    float* MOT = smem[half][0];
    float* D2T = smem[half][1];

    const float* MOb = MO   + (size_t)b * NELEC * NMO;
    const float* d2b = d2MO + (size_t)b * NELEC * NMO;

    // Stage MO^T and d2MO^T (512 floats each) with 128 threads: one float4 per
    // array per thread, fully coalesced. r = u/8 in 0..15, c = (u%8)*4.
    {
        int r = u >> 3;
        int c = (u & 7) * 4;
        float4 v = *(const float4*)(MOb + r * NMO + c);
        float4 w = *(const float4*)(d2b + r * NMO + c);
        MOT[(c + 0) * TSTR + r] = v.x;
        MOT[(c + 1) * TSTR + r] = v.y;
        MOT[(c + 2) * TSTR + r] = v.z;
        MOT[(c + 3) * TSTR + r] = v.w;
        D2T[(c + 0) * TSTR + r] = w.x;
        D2T[(c + 1) * TSTR + r] = w.y;
        D2T[(c + 2) * TSTR + r] = w.z;
        D2T[(c + 3) * TSTR + r] = w.w;
    }
    __syncthreads();

    const int cidx = u >> 1;                 // config index 0..63
    const int s    = u & 1;                  // 0 = up, 1 = down
    const int* cfg = s ? cfg_dn : cfg_up;
    int4 c0 = ((const int4*)cfg)[cidx * 2 + 0];
    int4 c1 = ((const int4*)cfg)[cidx * 2 + 1];
    const int cols[NS] = {c0.x, c0.y, c0.z, c0.w, c1.x, c1.y, c1.z, c1.w};

    float det, tr;
    solve8T(MOT, D2T, cols, s * NS, det, tr);

    // partner lane (u^1, same wave) holds the other spin channel
    float det_o = __shfl_xor(det, 1);
    float tr_o  = __shfl_xor(tr, 1);
    if (s == 0)
        out[(size_t)b * NCONF + cidx] = -0.5f * (tr + tr_o) * det * det_o;
}

extern "C" void kernel_launch(void* const* d_in, const int* in_sizes, int n_in,
                              void* d_out, int out_size, void* d_ws, size_t ws_size,
                              hipStream_t stream)
{
    const float* MO     = (const float*)d_in[0];
    const float* d2MO   = (const float*)d_in[1];
    const int*   cfg_up = (const int*)d_in[2];
    const int*   cfg_dn = (const int*)d_in[3];
    float* out = (float*)d_out;

    dim3 grid(NBATCH / 2);   // 4096 blocks, 2 batches per block, 2 threads per pair
    dim3 block(256);
    kp_pk_kernel<<<grid, block, 0, stream>>>(MO, d2MO, cfg_up, cfg_dn, out);
}